// Round 1
// baseline (726.506 us; speedup 1.0000x reference)
//
#include <hip/hip_runtime.h>

// Shapes: S=2048, B=2, H=1024, NH=16, DH=64, M=B*NH=32, 3H=3072, SB=S*B=4096
#define S_LEN 2048
#define ROWS 4096       // S*B
#define HDIM 1024
#define R3H 3072
#define M_HEADS 32
#define DH 64

typedef short short8 __attribute__((ext_vector_type(8)));
typedef __bf16 bf16x8 __attribute__((ext_vector_type(8)));
typedef float f32x4 __attribute__((ext_vector_type(4)));

static __device__ __forceinline__ short f2bf(float f) {
    unsigned u = __builtin_bit_cast(unsigned, f);
    unsigned r = (u + 0x7FFF + ((u >> 16) & 1)) >> 16;
    return (short)r;
}

static __device__ __forceinline__ bf16x8 ld_bf8(const short* p) {
    return __builtin_bit_cast(bf16x8, *(const short8*)p);
}

__global__ __launch_bounds__(256) void cast_bf16(const float* __restrict__ src,
                                                 short* __restrict__ dst, int n) {
    int i = (blockIdx.x * 256 + threadIdx.x) * 8;
    if (i >= n) return;
    float4 a = *(const float4*)(src + i);
    float4 b = *(const float4*)(src + i + 4);
    short8 o;
    o[0] = f2bf(a.x); o[1] = f2bf(a.y); o[2] = f2bf(a.z); o[3] = f2bf(a.w);
    o[4] = f2bf(b.x); o[5] = f2bf(b.y); o[6] = f2bf(b.z); o[7] = f2bf(b.w);
    *(short8*)(dst + i) = o;
}

// QKV projection: out[r][c] = sum_k hidden[r][k] * W[c][k] + bias[c]
// r = s*2+b (rows of hidden flattened), c = h*192 + seg*64 + d.
// Writes Q/K/V bf16 [m=b*16+h][s][d] and sq/sk fp32 [m][s].
__global__ __launch_bounds__(256) void qkv_gemm(const short* __restrict__ hb,
                                                const short* __restrict__ wb,
                                                const float* __restrict__ bias,
                                                short* __restrict__ Qb,
                                                short* __restrict__ Kb,
                                                short* __restrict__ Vb,
                                                float* __restrict__ sq,
                                                float* __restrict__ sk) {
    const int c0 = blockIdx.x * 64;
    const int r0 = blockIdx.y * 64;
    const int tid = threadIdx.x;
    const int wave = tid >> 6, lane = tid & 63;
    const int quad = lane >> 4, l16 = lane & 15;

    // stride 56 shorts = 112B: multiple of 16B (b128-aligned), 2-way-only bank aliasing
    __shared__ __align__(16) short Asm[64 * 56];
    __shared__ __align__(16) short Bsm[64 * 56];

    f32x4 acc[4];
#pragma unroll
    for (int nt = 0; nt < 4; ++nt) acc[nt] = (f32x4){0.f, 0.f, 0.f, 0.f};

    const int srow = tid >> 2;           // 0..63
    const int sko = (tid & 3) * 8;       // 0,8,16,24

    for (int k0 = 0; k0 < HDIM; k0 += 32) {
        short8 va = *(const short8*)&hb[(r0 + srow) * HDIM + k0 + sko];
        short8 vb8 = *(const short8*)&wb[(c0 + srow) * HDIM + k0 + sko];
        __syncthreads();
        *(short8*)&Asm[srow * 56 + sko] = va;
        *(short8*)&Bsm[srow * 56 + sko] = vb8;
        __syncthreads();

        bf16x8 a = ld_bf8(&Asm[(wave * 16 + l16) * 56 + quad * 8]);
#pragma unroll
        for (int nt = 0; nt < 4; ++nt) {
            bf16x8 b = ld_bf8(&Bsm[(nt * 16 + l16) * 56 + quad * 8]);
            acc[nt] = __builtin_amdgcn_mfma_f32_16x16x32_bf16(a, b, acc[nt], 0, 0, 0);
        }
    }

    const int seg = (c0 % 192) / 64;     // 0=Q, 1=K, 2=V
    const int h = c0 / 192;
    short* dst = (seg == 0) ? Qb : (seg == 1) ? Kb : Vb;
    float* dsq = (seg == 0) ? sq : sk;
    const int rbase = r0 + wave * 16 + quad * 4;

#pragma unroll
    for (int reg = 0; reg < 4; ++reg) {
        int r = rbase + reg;
        int s = r >> 1, bb = r & 1;
        int mh = bb * 16 + h;
        float part = 0.f;
#pragma unroll
        for (int nt = 0; nt < 4; ++nt) {
            float v = acc[nt][reg] + bias[c0 + nt * 16 + l16];
            int d = nt * 16 + l16;
            dst[(mh * S_LEN + s) * DH + d] = f2bf(v);
            part += v * v;
        }
        if (seg < 2) {
            part += __shfl_xor(part, 1);
            part += __shfl_xor(part, 2);
            part += __shfl_xor(part, 4);
            part += __shfl_xor(part, 8);
            if (l16 == 0) dsq[mh * S_LEN + s] = part;
        }
    }
}

// Fused attention: per (m, s-tile 64) block, loop t in chunks of 64.
// scores -> out1 (fp32), ctx accumulate -> out0.
__global__ __launch_bounds__(256) void attn(const short* __restrict__ Qb,
                                            const short* __restrict__ Kb,
                                            const short* __restrict__ Vb,
                                            const float* __restrict__ sq,
                                            const float* __restrict__ sk,
                                            float* __restrict__ out0,
                                            float* __restrict__ out1) {
    const int m = blockIdx.x;            // 0..31
    const int s0 = blockIdx.y * 64;
    const int tid = threadIdx.x;
    const int wave = tid >> 6, lane = tid & 63;
    const int quad = lane >> 4, l16 = lane & 15;

    __shared__ __align__(16) short Ksm[64 * 72];      // [t][d] stride 72
    __shared__ __align__(16) short Vsm[64 * 72];      // [d][t] stride 72 (transposed)
    __shared__ __align__(16) short Psm[4][16 * 72];   // per-wave probs [s][t]
    __shared__ float sksm[64];

    // Q fragments held in registers for the whole block
    const int srow = s0 + wave * 16 + l16;
    bf16x8 qf0 = ld_bf8(&Qb[(m * S_LEN + srow) * DH + quad * 8]);
    bf16x8 qf1 = ld_bf8(&Qb[(m * S_LEN + srow) * DH + 32 + quad * 8]);

    float sq4[4];
#pragma unroll
    for (int reg = 0; reg < 4; ++reg)
        sq4[reg] = sq[m * S_LEN + s0 + wave * 16 + quad * 4 + reg];

    f32x4 ctx[4];
#pragma unroll
    for (int nt = 0; nt < 4; ++nt) ctx[nt] = (f32x4){0.f, 0.f, 0.f, 0.f};

    const int trow = tid >> 2;           // 0..63
    const int cbase = (tid & 3) * 16;    // 0,16,32,48

    for (int t0 = 0; t0 < S_LEN; t0 += 64) {
        // global loads (before barrier)
        const short* kg = &Kb[(m * S_LEN + t0 + trow) * DH + cbase];
        const short* vg = &Vb[(m * S_LEN + t0 + trow) * DH + cbase];
        short8 kv0 = *(const short8*)kg;
        short8 kv1 = *(const short8*)(kg + 8);
        short8 vv0 = *(const short8*)vg;
        short8 vv1 = *(const short8*)(vg + 8);
        float skl = (tid < 64) ? sk[m * S_LEN + t0 + tid] : 0.f;

        __syncthreads();
        *(short8*)&Ksm[trow * 72 + cbase] = kv0;
        *(short8*)&Ksm[trow * 72 + cbase + 8] = kv1;
#pragma unroll
        for (int e = 0; e < 8; ++e) {
            Vsm[(cbase + e) * 72 + trow] = vv0[e];
            Vsm[(cbase + 8 + e) * 72 + trow] = vv1[e];
        }
        if (tid < 64) sksm[tid] = skl;
        __syncthreads();

        // QK^T, scores, exp, stage P
#pragma unroll
        for (int nt = 0; nt < 4; ++nt) {
            bf16x8 b0 = ld_bf8(&Ksm[(nt * 16 + l16) * 72 + quad * 8]);
            bf16x8 b1 = ld_bf8(&Ksm[(nt * 16 + l16) * 72 + 32 + quad * 8]);
            f32x4 a = (f32x4){0.f, 0.f, 0.f, 0.f};
            a = __builtin_amdgcn_mfma_f32_16x16x32_bf16(qf0, b0, a, 0, 0, 0);
            a = __builtin_amdgcn_mfma_f32_16x16x32_bf16(qf1, b1, a, 0, 0, 0);
            float skv = sksm[nt * 16 + l16];
#pragma unroll
            for (int reg = 0; reg < 4; ++reg) {
                int s = s0 + wave * 16 + quad * 4 + reg;
                float sc = (sq4[reg] + skv - 2.f * a[reg]) * -0.0625f;
                out1[(size_t)m * S_LEN * S_LEN + (size_t)s * S_LEN + t0 + nt * 16 + l16] = sc;
                Psm[wave][(quad * 4 + reg) * 72 + nt * 16 + l16] = f2bf(__expf(sc));
            }
        }

        // P @ V (P is per-wave; in-wave LDS ordering handled by waitcnt)
        bf16x8 p0 = ld_bf8(&Psm[wave][l16 * 72 + quad * 8]);
        bf16x8 p1 = ld_bf8(&Psm[wave][l16 * 72 + 32 + quad * 8]);
#pragma unroll
        for (int nt = 0; nt < 4; ++nt) {
            bf16x8 v0 = ld_bf8(&Vsm[(nt * 16 + l16) * 72 + quad * 8]);
            bf16x8 v1 = ld_bf8(&Vsm[(nt * 16 + l16) * 72 + 32 + quad * 8]);
            ctx[nt] = __builtin_amdgcn_mfma_f32_16x16x32_bf16(p0, v0, ctx[nt], 0, 0, 0);
            ctx[nt] = __builtin_amdgcn_mfma_f32_16x16x32_bf16(p1, v1, ctx[nt], 0, 0, 0);
        }
    }

    // ctx -> out0[s*2048 + b*1024 + h*64 + d]
    const int bb = m >> 4, h = m & 15;
#pragma unroll
    for (int nt = 0; nt < 4; ++nt) {
#pragma unroll
        for (int reg = 0; reg < 4; ++reg) {
            int s = s0 + wave * 16 + quad * 4 + reg;
            int d = nt * 16 + l16;
            out0[(size_t)s * 2048 + bb * 1024 + h * 64 + d] = ctx[nt][reg];
        }
    }
}

extern "C" void kernel_launch(void* const* d_in, const int* in_sizes, int n_in,
                              void* d_out, int out_size, void* d_ws, size_t ws_size,
                              hipStream_t stream) {
    const float* hidden = (const float*)d_in[0];   // [2048,2,1024]
    const float* W = (const float*)d_in[1];        // [3072,1024]
    const float* bias = (const float*)d_in[2];     // [3072]
    float* out0 = (float*)d_out;                   // ctx: 4,194,304 floats
    float* out1 = out0 + (size_t)ROWS * HDIM;      // scores: 134,217,728 floats

    short* hb = (short*)d_ws;                      // 4,194,304 shorts
    short* wb = hb + (size_t)ROWS * HDIM;          // 3,145,728 shorts
    short* Qb = wb + (size_t)R3H * HDIM;           // 4,194,304 shorts each
    short* Kb = Qb + (size_t)M_HEADS * S_LEN * DH;
    short* Vb = Kb + (size_t)M_HEADS * S_LEN * DH;
    float* sq = (float*)(Vb + (size_t)M_HEADS * S_LEN * DH);
    float* sk = sq + M_HEADS * S_LEN;

    cast_bf16<<<ROWS * HDIM / (8 * 256), 256, 0, stream>>>(hidden, hb, ROWS * HDIM);
    cast_bf16<<<R3H * HDIM / (8 * 256), 256, 0, stream>>>(W, wb, R3H * HDIM);
    qkv_gemm<<<dim3(R3H / 64, ROWS / 64), 256, 0, stream>>>(hb, wb, bias, Qb, Kb, Vb, sq, sk);
    attn<<<dim3(M_HEADS, S_LEN / 64), 256, 0, stream>>>(Qb, Kb, Vb, sq, sk, out0, out1);
}